// Round 1
// baseline (18489.368 us; speedup 1.0000x reference)
//
#include <hip/hip_runtime.h>
#include <hip/hip_bf16.h>

#define NSITES 256
#define NM 128        // nup == ndn
#define NMODES 512

typedef unsigned long long u64;
typedef unsigned int u32;

__device__ __forceinline__ u64 pivkey(float v, int i, int k) {
  if (i < k) return 0ull;
  u32 ab = __float_as_uint(fabsf(v));
  return ((u64)ab << 32) | (u32)i;
}

// selector args are wave-uniform (derived from loop counter / readfirstlane)
__device__ __forceinline__ void extract_col(float (&dst)[8], const float (&a)[8][8], int jj_sel) {
#pragma unroll
  for (int jj = 0; jj < 8; ++jj)
    if (jj == jj_sel) {
#pragma unroll
      for (int ii = 0; ii < 8; ++ii) dst[ii] = a[ii][jj];
    }
}
__device__ __forceinline__ void extract_row(float (&dst)[8], const float (&a)[8][8], int ii_sel) {
#pragma unroll
  for (int ii = 0; ii < 8; ++ii)
    if (ii == ii_sel) {
#pragma unroll
      for (int jj = 0; jj < 8; ++jj) dst[jj] = a[ii][jj];
    }
}
__device__ __forceinline__ void insert_row(float (&a)[8][8], int ii_sel, const float (&src)[8]) {
#pragma unroll
  for (int ii = 0; ii < 8; ++ii)
    if (ii == ii_sel) {
#pragma unroll
      for (int jj = 0; jj < 8; ++jj) a[ii][jj] = src[jj];
    }
}

// One block per (batch, spin). 256 threads, register-resident 128x128 LU
// with partial pivoting. Thread (tx,ty) owns A[i][j] for i%16==ty, j%16==tx.
__global__ __launch_bounds__(256) void lu_kernel(
    const int* __restrict__ n, const float* __restrict__ phi_up,
    const float* __restrict__ phi_dn, float* __restrict__ ws, int B)
{
  __shared__ int occ[NSITES];       // only NM used
  __shared__ int wcnt[4];
  __shared__ float colbuf[NM];
  __shared__ float colm[NM];
  __shared__ float rowK[NM];
  __shared__ float rowP[NM];
  __shared__ u64 skey;

  const int t = threadIdx.x;
  const int tx = t & 15, ty = t >> 4;
  const int bs = blockIdx.x;
  const int b = bs >> 1, spin = bs & 1;
  const int* nn = n + b * NMODES + spin * NSITES;
  const float* phi = spin ? phi_dn : phi_up;

  // ---- occupied-site list (exactly NM entries, ascending) ----
  {
    int v = nn[t];
    u64 m = __ballot(v != 0);
    int lane = t & 63, wv = t >> 6;
    if (lane == 0) wcnt[wv] = __popcll(m);
    __syncthreads();
    int off = 0;
    for (int w = 0; w < wv; ++w) off += wcnt[w];
    if (v) occ[off + __popcll(m & ((1ull << lane) - 1))] = t;
    __syncthreads();
  }

  // ---- gather matrix into registers ----
  float a[8][8];
#pragma unroll
  for (int ii = 0; ii < 8; ++ii) {
    const float* prow = phi + occ[ii * 16 + ty] * NM;
#pragma unroll
    for (int jj = 0; jj < 8; ++jj) a[ii][jj] = prow[jj * 16 + tx];
  }
  __syncthreads();

  // ---- LU with partial pivoting ----
  float logabs = 0.f;
  int sb = 0;
  for (int k = 0; k < NM; ++k) {
    const int kb = k >> 4, kk = k & 15;

    // S0: publish current column k
    {
      float cv[8];
      extract_col(cv, a, kb);
      if (tx == kk) {
#pragma unroll
        for (int ii = 0; ii < 8; ++ii) colbuf[ii * 16 + ty] = cv[ii];
      }
    }
    __syncthreads();  // B1

    // S1: argmax |col[i]| for i >= k
    if (t < 64) {
      u64 k1 = pivkey(colbuf[t], t, k);
      u64 k2 = pivkey(colbuf[t + 64], t + 64, k);
      u64 km = k1 > k2 ? k1 : k2;
#pragma unroll
      for (int d = 32; d >= 1; d >>= 1) {
        u64 o = __shfl_down(km, d);
        if (o > km) km = o;
      }
      if (t == 0) skey = km;
    }
    __syncthreads();  // B2

    const u64 key = skey;
    const int p = __builtin_amdgcn_readfirstlane((int)(key & 0xffffffffu));
    const int pb = p >> 4, pt = p & 15;
    const float piv = colbuf[p];

    // S2: stage rows k and p for the swap; multipliers (0 for i<=k)
    {
      float rv[8];
      extract_row(rv, a, kb);
      if (ty == kk) {
#pragma unroll
        for (int jj = 0; jj < 8; ++jj) rowK[jj * 16 + tx] = rv[jj];
      }
      extract_row(rv, a, pb);
      if (ty == pt) {
#pragma unroll
        for (int jj = 0; jj < 8; ++jj) rowP[jj * 16 + tx] = rv[jj];
      }
    }
    if (t < NM) {
      float mv = 0.f;
      if (t > k) {
        float cvv = colbuf[(t == p) ? k : t];  // column value after logical swap
        mv = cvv / piv;
      }
      colm[t] = mv;
    }
    __syncthreads();  // B3

    // S3: swap read-back + rank-1 update (masking via zeros in cm/pr)
    float pr[8], cm[8];
#pragma unroll
    for (int jj = 0; jj < 8; ++jj) {
      float vv = rowP[jj * 16 + tx];
      int j = jj * 16 + tx;
      pr[jj] = (j >= k) ? vv : 0.f;
    }
    if (ty == kk) insert_row(a, kb, pr);          // new row k = old row p
    if (p != k && ty == pt) {
      float rk[8];
#pragma unroll
      for (int jj = 0; jj < 8; ++jj) rk[jj] = rowK[jj * 16 + tx];
      insert_row(a, pb, rk);                      // new row p = old row k
    }
#pragma unroll
    for (int ii = 0; ii < 8; ++ii) cm[ii] = colm[ii * 16 + ty];
#pragma unroll
    for (int ii = 0; ii < 8; ++ii)
#pragma unroll
      for (int jj = 0; jj < 8; ++jj)
        a[ii][jj] = fmaf(-cm[ii], pr[jj], a[ii][jj]);

    logabs += logf(fabsf(piv));
    sb ^= (__float_as_uint(piv) >> 31);
    sb ^= (p != k) ? 1 : 0;
    // no end barrier needed: next iter's B1 orders colbuf writes vs S1 reads,
    // and B2/B3 order rowK/rowP/colm writes vs this iter's S3 reads.
  }

  if (t == 0) {
    ws[B + spin * B + b] = logabs;                       // logabs: [B, 3B)
    ws[3 * B + spin * B + b] = (sb & 1) ? -1.f : 1.f;    // sign:   [3B, 5B)
  }
}

// One block per batch: log_j = -0.5 * sum_{i occ} sum_c v[i][c] * nf[c]
__global__ __launch_bounds__(256) void jastrow_kernel(
    const int* __restrict__ n, const float* __restrict__ v,
    float* __restrict__ ws, int B)
{
  __shared__ int occ[256];
  __shared__ float nf[NMODES];
  __shared__ int wcnt[8];
  __shared__ float red[256];
  const int t = threadIdx.x, b = blockIdx.x;
  const int lane = t & 63, wv = t >> 6;
  const int* nn = n + b * NMODES;
  int v0 = nn[t], v1 = nn[256 + t];
  nf[t] = (float)v0;
  nf[256 + t] = (float)v1;
  u64 m0 = __ballot(v0 != 0), m1 = __ballot(v1 != 0);
  if (lane == 0) { wcnt[wv] = __popcll(m0); wcnt[4 + wv] = __popcll(m1); }
  __syncthreads();
  int off0 = 0;
  for (int w = 0; w < wv; ++w) off0 += wcnt[w];
  int base1 = wcnt[0] + wcnt[1] + wcnt[2] + wcnt[3];
  int off1 = base1;
  for (int w = 0; w < wv; ++w) off1 += wcnt[4 + w];
  if (v0) occ[off0 + __popcll(m0 & ((1ull << lane) - 1))] = t;
  if (v1) occ[off1 + __popcll(m1 & ((1ull << lane) - 1))] = 256 + t;
  __syncthreads();

  float acc = 0.f;
  for (int r = wv * 64; r < wv * 64 + 64; ++r) {
    const float* row = v + occ[r] * NMODES;   // occ[r] wave-uniform -> broadcast
#pragma unroll
    for (int cc = 0; cc < 8; ++cc) {
      int c = cc * 64 + lane;                 // coalesced 256B per iter
      acc += row[c] * nf[c];
    }
  }
  red[t] = acc;
  __syncthreads();
  for (int s = 128; s >= 1; s >>= 1) {
    if (t < s) red[t] += red[t + s];
    __syncthreads();
  }
  if (t == 0) ws[b] = -0.5f * red[0];
}

__global__ void finalize_kernel(const float* __restrict__ ws,
                                float* __restrict__ out, int B)
{
  int b = blockIdx.x * 256 + threadIdx.x;
  if (b < B) {
    float lj = ws[b];
    float la_u = ws[B + b], la_d = ws[2 * B + b];
    float s_u = ws[3 * B + b], s_d = ws[4 * B + b];
    out[b] = s_u * s_d;
    out[B + b] = lj + la_u + la_d;
  }
}

extern "C" void kernel_launch(void* const* d_in, const int* in_sizes, int n_in,
                              void* d_out, int out_size, void* d_ws, size_t ws_size,
                              hipStream_t stream) {
  const int* n = (const int*)d_in[0];
  const float* phi_up = (const float*)d_in[1];
  const float* phi_dn = (const float*)d_in[2];
  const float* v = (const float*)d_in[3];
  float* out = (float*)d_out;
  float* ws = (float*)d_ws;
  const int B = in_sizes[0] / NMODES;  // 4096

  jastrow_kernel<<<B, 256, 0, stream>>>(n, v, ws, B);
  lu_kernel<<<2 * B, 256, 0, stream>>>(n, phi_up, phi_dn, ws, B);
  finalize_kernel<<<(B + 255) / 256, 256, 0, stream>>>(ws, out, B);
}

// Round 2
// 2380.191 us; speedup vs baseline: 7.7680x; 7.7680x over previous
//
#include <hip/hip_runtime.h>
#include <hip/hip_bf16.h>

#define NSITES 256
#define NM 128        // nup == ndn
#define NMODES 512

typedef unsigned long long u64;
typedef unsigned int u32;

#define REP8(M)    M(0) M(1) M(2) M(3) M(4) M(5) M(6) M(7)
#define REP8P(M,P) M(0,P) M(1,P) M(2,P) M(3,P) M(4,P) M(5,P) M(6,P) M(7,P)

// One block per (batch, spin). 256 threads, register-resident 128x128 LU with
// partial pivoting. Thread (tx,ty) owns A[i][j] for i%16==ty, j%16==tx, stored
// a[II][JJ] = A[II*16+ty][JJ*16+tx]. ALL register indices are preprocessor
// literals (SROA runs before unrolling -> pragma-unrolled runtime indices
// caused a 98GB scratch spill in round 1).
__global__ __launch_bounds__(256, 4) void lu_kernel(
    const int* __restrict__ n, const float* __restrict__ phi_up,
    const float* __restrict__ phi_dn, float* __restrict__ ws, int B)
{
  __shared__ int occ[NSITES];
  __shared__ int wcnt[4];
  __shared__ float colbuf[2][NM];   // double-buffered by k parity
  __shared__ float rowK[NM], rowP[NM];

  const int t = threadIdx.x;
  const int tx = t & 15, ty = t >> 4;
  const int lane = t & 63, wv = t >> 6;
  const int bs = blockIdx.x;
  const int b = bs >> 1, spin = bs & 1;
  const int* nn = n + b * NMODES + spin * NSITES;
  const float* phi = spin ? phi_dn : phi_up;

  // ---- occupied-site list (exactly NM entries, ascending) ----
  {
    int v = nn[t];
    u64 m = __ballot(v != 0);
    if (lane == 0) wcnt[wv] = __popcll(m);
    __syncthreads();
    int off = 0;
    for (int w = 0; w < wv; ++w) off += wcnt[w];
    if (v) occ[off + __popcll(m & ((1ull << lane) - 1))] = t;
    __syncthreads();
  }

  // ---- gather matrix into registers (static indices only) ----
  float a[8][8];
#define GATH(II) { const float* pr_ = phi + occ[(II)*16 + ty] * NM; \
  a[II][0] = pr_[0*16+tx]; a[II][1] = pr_[1*16+tx]; \
  a[II][2] = pr_[2*16+tx]; a[II][3] = pr_[3*16+tx]; \
  a[II][4] = pr_[4*16+tx]; a[II][5] = pr_[5*16+tx]; \
  a[II][6] = pr_[6*16+tx]; a[II][7] = pr_[7*16+tx]; }
  REP8(GATH)
#undef GATH

  // ---- prologue: publish column 0 into colbuf[0] ----
  if (tx == 0) {
#define PUB0(II) colbuf[0][(II)*16 + ty] = a[II][0];
    REP8(PUB0)
#undef PUB0
  }

  float l2sum = 0.f;
  int sb = 0;

  for (int k = 0; k < NM; ++k) {
    const int cur = k & 1, nxt = cur ^ 1;
    const int kb = k >> 4, kk = k & 15;
    __syncthreads();  // B1: colbuf[cur] ready; prev iter's rowK/rowP reads done

    // ---- wave-parallel argmax of |col[i]|, i >= k (redundant per wave) ----
    const float v1 = colbuf[cur][lane];
    const float v2 = colbuf[cur][lane + 64];
    const float c1 = (lane      >= k) ? fabsf(v1) : -1.0f;
    const float c2 = (lane + 64 >= k) ? fabsf(v2) : -1.0f;
    float mx = fmaxf(c1, c2);
#pragma unroll
    for (int d = 1; d < 64; d <<= 1) mx = fmaxf(mx, __shfl_xor(mx, d));
    const u64 b1m = __ballot(c1 == mx);
    const u64 b2m = __ballot(c2 == mx);
    int p = b1m ? (__ffsll(b1m) - 1) : (__ffsll(b2m) + 63);
    p = __builtin_amdgcn_readfirstlane(p);
    const int pb = p >> 4, pt = p & 15;
    const float piv  = colbuf[cur][p];
    const float colk = colbuf[cur][k];
    const float rpiv = 1.0f / piv;

    // ---- stage old rows k and p (pre-swap values) ----
    if (ty == kk) {
      switch (kb) {
#define SRK(II) case II: \
  rowK[0*16+tx]=a[II][0]; rowK[1*16+tx]=a[II][1]; rowK[2*16+tx]=a[II][2]; rowK[3*16+tx]=a[II][3]; \
  rowK[4*16+tx]=a[II][4]; rowK[5*16+tx]=a[II][5]; rowK[6*16+tx]=a[II][6]; rowK[7*16+tx]=a[II][7]; break;
        REP8(SRK)
#undef SRK
      }
    }
    if (ty == pt) {
      switch (pb) {
#define SRP(II) case II: \
  rowP[0*16+tx]=a[II][0]; rowP[1*16+tx]=a[II][1]; rowP[2*16+tx]=a[II][2]; rowP[3*16+tx]=a[II][3]; \
  rowP[4*16+tx]=a[II][4]; rowP[5*16+tx]=a[II][5]; rowP[6*16+tx]=a[II][6]; rowP[7*16+tx]=a[II][7]; break;
        REP8(SRP)
#undef SRP
      }
    }
    __syncthreads();  // B2: rowK/rowP staged

    // ---- row swap in registers ----
    if (ty == kk) {
      switch (kb) {
#define IRK(II) case II: \
  a[II][0]=rowP[0*16+tx]; a[II][1]=rowP[1*16+tx]; a[II][2]=rowP[2*16+tx]; a[II][3]=rowP[3*16+tx]; \
  a[II][4]=rowP[4*16+tx]; a[II][5]=rowP[5*16+tx]; a[II][6]=rowP[6*16+tx]; a[II][7]=rowP[7*16+tx]; break;
        REP8(IRK)
#undef IRK
      }
    }
    if (p != k && ty == pt) {
      switch (pb) {
#define IRP(II) case II: \
  a[II][0]=rowK[0*16+tx]; a[II][1]=rowK[1*16+tx]; a[II][2]=rowK[2*16+tx]; a[II][3]=rowK[3*16+tx]; \
  a[II][4]=rowK[4*16+tx]; a[II][5]=rowK[5*16+tx]; a[II][6]=rowK[6*16+tx]; a[II][7]=rowK[7*16+tx]; break;
        REP8(IRP)
#undef IRP
      }
    }

    // ---- multipliers + pivot row + rank-1 update, specialized per kb ----
    // Rows/cols in blocks < kb are already eliminated (cm=0 / pr=0) -> skip.
    float cm[8], pr[8];
#define CME(II, KB) if ((II) >= (KB)) { const int i_ = (II)*16 + ty; \
  const float cv_ = (i_ == p) ? colk : colbuf[cur][i_]; \
  cm[II] = (i_ > k) ? cv_ * rpiv : 0.f; }
#define PRE(JJ, KB) if ((JJ) >= (KB)) pr[JJ] = rowP[(JJ)*16 + tx];
#define UPDROW(II, KB) if ((II) >= (KB)) { const float m_##II = -cm[II]; \
  if (0 >= (KB)) a[II][0] = fmaf(m_##II, pr[0], a[II][0]); \
  if (1 >= (KB)) a[II][1] = fmaf(m_##II, pr[1], a[II][1]); \
  if (2 >= (KB)) a[II][2] = fmaf(m_##II, pr[2], a[II][2]); \
  if (3 >= (KB)) a[II][3] = fmaf(m_##II, pr[3], a[II][3]); \
  if (4 >= (KB)) a[II][4] = fmaf(m_##II, pr[4], a[II][4]); \
  if (5 >= (KB)) a[II][5] = fmaf(m_##II, pr[5], a[II][5]); \
  if (6 >= (KB)) a[II][6] = fmaf(m_##II, pr[6], a[II][6]); \
  if (7 >= (KB)) a[II][7] = fmaf(m_##II, pr[7], a[II][7]); }
#define LUCASE(KB) case KB: { REP8P(CME, KB) REP8P(PRE, KB) REP8P(UPDROW, KB) } break;
    switch (kb) {
      REP8(LUCASE)
    }
#undef LUCASE
#undef UPDROW
#undef PRE
#undef CME

    // ---- publish column k+1 (post-update) into colbuf[nxt] ----
    if (k + 1 < NM) {
      const int kn = k + 1;
      if (tx == (kn & 15)) {
        switch (kn >> 4) {
#define PUBC(JJ) case JJ: \
  colbuf[nxt][0*16+ty]=a[0][JJ]; colbuf[nxt][1*16+ty]=a[1][JJ]; \
  colbuf[nxt][2*16+ty]=a[2][JJ]; colbuf[nxt][3*16+ty]=a[3][JJ]; \
  colbuf[nxt][4*16+ty]=a[4][JJ]; colbuf[nxt][5*16+ty]=a[5][JJ]; \
  colbuf[nxt][6*16+ty]=a[6][JJ]; colbuf[nxt][7*16+ty]=a[7][JJ]; break;
          REP8(PUBC)
#undef PUBC
        }
      }
    }

    l2sum += __log2f(fabsf(piv));
    sb ^= (int)(__float_as_uint(piv) >> 31);
    sb ^= (p != k) ? 1 : 0;
  }

  if (t == 0) {
    ws[B + spin * B + b] = l2sum * 0.6931471805599453f;   // logabs: [B, 3B)
    ws[3 * B + spin * B + b] = (sb & 1) ? -1.f : 1.f;     // sign:   [3B, 5B)
  }
}

// One block per batch: log_j = -0.5 * sum_{i occ} sum_c v[i][c] * nf[c]
__global__ __launch_bounds__(256) void jastrow_kernel(
    const int* __restrict__ n, const float* __restrict__ v,
    float* __restrict__ ws, int B)
{
  __shared__ int occ[256];
  __shared__ float nf[NMODES];
  __shared__ int wcnt[8];
  __shared__ float red[256];
  const int t = threadIdx.x, b = blockIdx.x;
  const int lane = t & 63, wv = t >> 6;
  const int* nn = n + b * NMODES;
  int v0 = nn[t], v1 = nn[256 + t];
  nf[t] = (float)v0;
  nf[256 + t] = (float)v1;
  u64 m0 = __ballot(v0 != 0), m1 = __ballot(v1 != 0);
  if (lane == 0) { wcnt[wv] = __popcll(m0); wcnt[4 + wv] = __popcll(m1); }
  __syncthreads();
  int off0 = 0;
  for (int w = 0; w < wv; ++w) off0 += wcnt[w];
  int base1 = wcnt[0] + wcnt[1] + wcnt[2] + wcnt[3];
  int off1 = base1;
  for (int w = 0; w < wv; ++w) off1 += wcnt[4 + w];
  if (v0) occ[off0 + __popcll(m0 & ((1ull << lane) - 1))] = t;
  if (v1) occ[off1 + __popcll(m1 & ((1ull << lane) - 1))] = 256 + t;
  __syncthreads();

  float acc = 0.f;
  for (int r = wv * 64; r < wv * 64 + 64; ++r) {
    const float* row = v + occ[r] * NMODES;   // occ[r] wave-uniform -> broadcast
#pragma unroll
    for (int cc = 0; cc < 8; ++cc) {
      int c = cc * 64 + lane;                 // coalesced 256B per iter
      acc += row[c] * nf[c];
    }
  }
  red[t] = acc;
  __syncthreads();
  for (int s = 128; s >= 1; s >>= 1) {
    if (t < s) red[t] += red[t + s];
    __syncthreads();
  }
  if (t == 0) ws[b] = -0.5f * red[0];
}

__global__ void finalize_kernel(const float* __restrict__ ws,
                                float* __restrict__ out, int B)
{
  int b = blockIdx.x * 256 + threadIdx.x;
  if (b < B) {
    float lj = ws[b];
    float la_u = ws[B + b], la_d = ws[2 * B + b];
    float s_u = ws[3 * B + b], s_d = ws[4 * B + b];
    out[b] = s_u * s_d;
    out[B + b] = lj + la_u + la_d;
  }
}

extern "C" void kernel_launch(void* const* d_in, const int* in_sizes, int n_in,
                              void* d_out, int out_size, void* d_ws, size_t ws_size,
                              hipStream_t stream) {
  const int* n = (const int*)d_in[0];
  const float* phi_up = (const float*)d_in[1];
  const float* phi_dn = (const float*)d_in[2];
  const float* v = (const float*)d_in[3];
  float* out = (float*)d_out;
  float* ws = (float*)d_ws;
  const int B = in_sizes[0] / NMODES;  // 4096

  jastrow_kernel<<<B, 256, 0, stream>>>(n, v, ws, B);
  lu_kernel<<<2 * B, 256, 0, stream>>>(n, phi_up, phi_dn, ws, B);
  finalize_kernel<<<(B + 255) / 256, 256, 0, stream>>>(ws, out, B);
}